// Round 4
// baseline (243.164 us; speedup 1.0000x reference)
//
#include <hip/hip_runtime.h>
#include <stdint.h>

#define DEV __device__ __forceinline__

typedef float f32x4 __attribute__((ext_vector_type(4)));
typedef __bf16 bf16x8 __attribute__((ext_vector_type(8)));
typedef short short8 __attribute__((ext_vector_type(8)));
typedef short short4v __attribute__((ext_vector_type(4)));

DEV unsigned short f2bf(float f) {
    union { float f; unsigned u; } c; c.f = f;
    unsigned u = c.u;
    u += 0x7fffu + ((u >> 16) & 1u);   // round-to-nearest-even
    return (unsigned short)(u >> 16);
}

DEV void async_ld16(const void* g, void* l) {
    __builtin_amdgcn_global_load_lds(
        (const __attribute__((address_space(1))) unsigned int*)g,
        (__attribute__((address_space(3))) unsigned int*)l, 16, 0, 0);
}

DEV f32x4 mfma16(bf16x8 a, bf16x8 b, f32x4 c) {
    return __builtin_amdgcn_mfma_f32_16x16x32_bf16(a, b, c, 0, 0, 0);
}

// ---------------- k_prep: fused x->bf16 cvt + W transpose + flag zero -------
// blocks [0,4096): cvt; [4096,4864): trw; 4864: zero ctr
__global__ __launch_bounds__(256) void k_prep(const float* __restrict__ x,
                                              const float* __restrict__ W,
                                              unsigned short* __restrict__ xb,
                                              unsigned short* __restrict__ Wt,
                                              unsigned int* __restrict__ ctr) {
    __shared__ float T[64][65];
    int blk = blockIdx.x;
    if (blk < 4096) {
        int t = blk * 256 + threadIdx.x;
        const float4* xp = (const float4*)x;
        float4 a = xp[t * 2], b = xp[t * 2 + 1];
        short8 o;
        o[0] = (short)f2bf(a.x); o[1] = (short)f2bf(a.y);
        o[2] = (short)f2bf(a.z); o[3] = (short)f2bf(a.w);
        o[4] = (short)f2bf(b.x); o[5] = (short)f2bf(b.y);
        o[6] = (short)f2bf(b.z); o[7] = (short)f2bf(b.w);
        *(short8*)(xb + t * 8) = o;
    } else if (blk < 4864) {
        int bx = blk - 4096;
        int n0 = (bx % 48) * 64, k0 = (bx / 48) * 64;
        int t = threadIdx.x;
        int r = t >> 4, c4 = (t & 15) * 4;
        for (int i = 0; i < 4; i++) {
            int row = r + i * 16;
            float4 v = *(const float4*)(W + (k0 + row) * 3072 + n0 + c4);
            T[row][c4] = v.x; T[row][c4 + 1] = v.y; T[row][c4 + 2] = v.z; T[row][c4 + 3] = v.w;
        }
        __syncthreads();
        for (int i = 0; i < 4; i++) {
            int nrow = r + i * 16;
            short4v o;
            o[0] = (short)f2bf(T[c4 + 0][nrow]);
            o[1] = (short)f2bf(T[c4 + 1][nrow]);
            o[2] = (short)f2bf(T[c4 + 2][nrow]);
            o[3] = (short)f2bf(T[c4 + 3][nrow]);
            *(short4v*)(Wt + (n0 + nrow) * 1024 + k0 + c4) = o;
        }
    } else {
        if (threadIdx.x < 128) ctr[threadIdx.x] = 0u;
    }
}

// ---------------- QKV GEMM: [8192x1024]x[1024x3072] + bias, scatter --------
// Q stored [bh][n][d] scaled x32; K,V stored transposed [bh][d][n]
__global__ __launch_bounds__(256, 2) void k_qkv(const unsigned short* __restrict__ xb,
                                                const unsigned short* __restrict__ Wt,
                                                const float* __restrict__ bias,
                                                unsigned short* __restrict__ Q,
                                                unsigned short* __restrict__ K,
                                                unsigned short* __restrict__ V) {
    __shared__ __align__(16) unsigned short As[128 * 64];  // XOR-swizzled chunks (mask 7)
    __shared__ __align__(16) unsigned short Bs[128 * 64];
    const int m0 = blockIdx.y * 128, n0 = blockIdx.x * 128;
    const int wave = threadIdx.x >> 6, lane = threadIdx.x & 63;
    const int wm = (wave & 1) * 64, wn = (wave >> 1) * 64;
    f32x4 acc[4][4] = {};
    const int slr = wave * 32 + (lane >> 3);  // staging local row (+ i*8)
    const int scs = lane & 7;                 // staging chunk slot

    for (int kt = 0; kt < 16; kt++) {
        __syncthreads();
        for (int i = 0; i < 4; i++) {
            int lr = slr + i * 8;
            int c = scs ^ (lr & 7);
            async_ld16(xb + (m0 + lr) * 1024 + kt * 64 + c * 8,
                       (void*)(As + (wave * 32 + i * 8) * 64));
            async_ld16(Wt + (n0 + lr) * 1024 + kt * 64 + c * 8,
                       (void*)(Bs + (wave * 32 + i * 8) * 64));
        }
        __syncthreads();
        for (int ks = 0; ks < 2; ks++) {
            bf16x8 af[4], bfr[4];
            int c0 = ks * 4 + (lane >> 4);
            for (int tm = 0; tm < 4; tm++) {
                int row = wm + tm * 16 + (lane & 15);
                af[tm] = *(const bf16x8*)(As + row * 64 + (c0 ^ (row & 7)) * 8);
            }
            for (int tn = 0; tn < 4; tn++) {
                int row = wn + tn * 16 + (lane & 15);
                bfr[tn] = *(const bf16x8*)(Bs + row * 64 + (c0 ^ (row & 7)) * 8);
            }
            for (int tm = 0; tm < 4; tm++)
                for (int tn = 0; tn < 4; tn++)
                    acc[tm][tn] = mfma16(af[tm], bfr[tn], acc[tm][tn]);
        }
    }

    // epilogue: bias + scatter. col -> (h = c/192, d = (c%192)/3, which = c%3)
    const int batch = m0 >> 11;
    for (int tn = 0; tn < 4; tn++) {
        int col = n0 + wn + tn * 16 + (lane & 15);
        int h = col / 192;
        int rem = col - h * 192;
        int d = rem / 3;
        int which = rem - d * 3;
        float bv = bias[col];
        int bh = batch * 16 + h;
        unsigned q_base = (unsigned)bh * 131072u + (unsigned)d;          // [bh][n][d]
        unsigned kv_base = ((unsigned)bh * 64u + (unsigned)d) * 2048u;   // [bh][d][n]
        unsigned short* dst = which == 0 ? Q : (which == 1 ? K : V);
        float mult = which == 0 ? 32.0f : 1.0f;  // fold attn scale sqrt(1024)=32 into Q
        for (int tm = 0; tm < 4; tm++) {
            int rbase = m0 + wm + tm * 16 + ((lane >> 4) * 4);
            for (int r = 0; r < 4; r++) {
                int row = rbase + r;
                unsigned token = (unsigned)(row & 2047);
                float val = (acc[tm][tn][r] + bv) * mult;
                unsigned idx = (which == 0) ? (q_base + token * 64u) : (kv_base + token);
                dst[idx] = f2bf(val);
            }
        }
    }
}

// ---------------- k_attn2: fused (K^T V partials) + (Q . M) -----------------
// grid 512: block i -> bh = i>>3, sub = i&7.
// Phase A: Mpart[bh][sub] = K^T V over tokens [sub*256,+256), fp32 C-layout.
// Signal via per-head agent-scope counter (zeroed by k_prep).
// Phase B: wait ctr[bh]==8, sum partials -> bf16 M in LDS, out = Q.M for
// q-tile [sub*256,+256).  All 512 blocks co-resident (48KB LDS -> 3/CU).
__global__ __launch_bounds__(256) void k_attn2(const unsigned short* __restrict__ Kt,
                                               const unsigned short* __restrict__ Vt,
                                               const unsigned short* __restrict__ Q,
                                               float* __restrict__ Mpart,
                                               unsigned int* __restrict__ ctr,
                                               float* __restrict__ out) {
    __shared__ __align__(16) float Ss[3][4096];   // 48KB, reused as Msb in phase B
    const int i = blockIdx.x;
    const int bh = i >> 3, sub = i & 7;
    const int wave = threadIdx.x >> 6, lane = threadIdx.x & 63;
    const int lan15 = lane & 15, quad = lane >> 4;
    const unsigned base = (unsigned)bh * 131072u;

    // ---- phase A ----
    {
        const int n0w = sub * 256 + wave * 64;
        f32x4 acc[4][4] = {};
#pragma unroll
        for (int ks = 0; ks < 2; ks++) {
            bf16x8 af[4], bfr[4];
            int no = n0w + ks * 32 + quad * 8;
            for (int mt = 0; mt < 4; mt++)
                af[mt] = *(const bf16x8*)(Kt + base + (unsigned)(mt * 16 + lan15) * 2048u + no);
            for (int nt = 0; nt < 4; nt++)
                bfr[nt] = *(const bf16x8*)(Vt + base + (unsigned)(nt * 16 + lan15) * 2048u + no);
            for (int mt = 0; mt < 4; mt++)
                for (int nt = 0; nt < 4; nt++)
                    acc[mt][nt] = mfma16(af[mt], bfr[nt], acc[mt][nt]);
        }
        if (wave >= 1) {
            for (int mt = 0; mt < 4; mt++)
                for (int nt = 0; nt < 4; nt++)
                    *(f32x4*)(&Ss[wave - 1][((mt * 4 + nt) * 64 + lane) * 4]) = acc[mt][nt];
        }
        __syncthreads();
        if (wave == 0) {
            float* dst = Mpart + ((unsigned)bh * 8u + (unsigned)sub) * 4096u;
            for (int mt = 0; mt < 4; mt++)
                for (int nt = 0; nt < 4; nt++) {
                    f32x4 o = acc[mt][nt];
                    for (int s = 0; s < 3; s++) {
                        f32x4 p = *(const f32x4*)(&Ss[s][((mt * 4 + nt) * 64 + lane) * 4]);
                        o.x += p.x; o.y += p.y; o.z += p.z; o.w += p.w;
                    }
                    *(f32x4*)(dst + ((mt * 4 + nt) * 64 + lane) * 4) = o;
                }
            __threadfence();
            if (lane == 0)
                __hip_atomic_fetch_add(&ctr[bh], 1u, __ATOMIC_RELEASE, __HIP_MEMORY_SCOPE_AGENT);
        }
    }

    // ---- wait for all 8 partials of this head ----
    if (threadIdx.x == 0) {
        while (__hip_atomic_load(&ctr[bh], __ATOMIC_ACQUIRE, __HIP_MEMORY_SCOPE_AGENT) < 8u)
            __builtin_amdgcn_s_sleep(8);
    }
    __syncthreads();

    // ---- phase B preamble: sum 8 partials, decode C-layout, bf16 to LDS ----
    unsigned short* Msb = (unsigned short*)&Ss[0][0];   // [d2][d1 xor-swizzled], 8KB
    {
        const float* mp = Mpart + (unsigned)bh * 8u * 4096u;
        int e0 = threadIdx.x * 16;
        for (int j = 0; j < 4; j++) {
            f32x4 m = *(const f32x4*)(mp + e0 + j * 4);
            for (int s = 1; s < 8; s++) {
                f32x4 p = *(const f32x4*)(mp + s * 4096 + e0 + j * 4);
                m.x += p.x; m.y += p.y; m.z += p.z; m.w += p.w;
            }
            for (int r = 0; r < 4; r++) {
                int e = e0 + j * 4 + r;
                int tile = e >> 8, le = (e >> 2) & 63;
                int d1 = (tile >> 2) * 16 + ((le >> 4) << 2) + r;
                int d2 = (tile & 3) * 16 + (le & 15);
                Msb[d2 * 64 + (((d1 >> 3) ^ (d2 & 7)) << 3) + (d1 & 7)] = f2bf(m[r]);
            }
        }
    }
    __syncthreads();

    // ---- phase B main: out tile = Q(x32)[q-range] . M ----
    {
        const int q0w = sub * 256 + wave * 64;
        f32x4 oacc[4][4] = {};
#pragma unroll
        for (int ks = 0; ks < 2; ks++) {
            bf16x8 af[4], bfr[4];
            for (int mt = 0; mt < 4; mt++)
                af[mt] = *(const bf16x8*)(Q + base + (unsigned)(q0w + mt * 16 + lan15) * 64u +
                                          ks * 32 + quad * 8);
            for (int nt = 0; nt < 4; nt++) {
                int d2 = nt * 16 + lan15;
                bfr[nt] = *(const bf16x8*)(Msb + d2 * 64 + (((ks * 4 + quad) ^ (d2 & 7)) << 3));
            }
            for (int mt = 0; mt < 4; mt++)
                for (int nt = 0; nt < 4; nt++)
                    oacc[mt][nt] = mfma16(af[mt], bfr[nt], oacc[mt][nt]);
        }
        for (int mt = 0; mt < 4; mt++)
            for (int nt = 0; nt < 4; nt++)
                for (int r = 0; r < 4; r++)
                    out[base + (unsigned)(q0w + mt * 16 + quad * 4 + r) * 64u + nt * 16 + lan15] =
                        oacc[mt][nt][r];
    }
}

extern "C" void kernel_launch(void* const* d_in, const int* in_sizes, int n_in,
                              void* d_out, int out_size, void* d_ws, size_t ws_size,
                              hipStream_t stream) {
    const float* x = (const float*)d_in[0];
    const float* W = (const float*)d_in[1];
    const float* b = (const float*)d_in[2];
    float* out = (float*)d_out;

    unsigned short* xb = (unsigned short*)d_ws;   // 8,388,608 bf16 (16 MB)
    unsigned short* Wt = xb + 8388608;            // 3,145,728 bf16 (6 MB)
    unsigned short* Qb = Wt + 3145728;            // 8,388,608 bf16 (scaled by 32)
    unsigned short* Kt = Qb + 8388608;            // 8,388,608 bf16, [bh][d][n]
    unsigned short* Vt = Kt + 8388608;            // 8,388,608 bf16, [bh][d][n]
    unsigned int* ctr = (unsigned int*)(Vt + 8388608);  // 128 u32 flags
    // Mpart aliases xb: xb dead after k_qkv (stream order). 64*8*4096 f32 = 8 MB
    float* Mpart = (float*)d_ws;
    // total workspace: ~70.5 MB

    k_prep<<<4865, 256, 0, stream>>>(x, W, xb, Wt, ctr);
    k_qkv<<<dim3(24, 64), 256, 0, stream>>>(xb, Wt, b, Qb, Kt, Vt);
    k_attn2<<<512, 256, 0, stream>>>(Kt, Vt, Qb, Mpart, ctr, out);
}

// Round 5
// 184.873 us; speedup vs baseline: 1.3153x; 1.3153x over previous
//
#include <hip/hip_runtime.h>
#include <stdint.h>

#define DEV __device__ __forceinline__

typedef float f32x4 __attribute__((ext_vector_type(4)));
typedef __bf16 bf16x8 __attribute__((ext_vector_type(8)));
typedef short short8 __attribute__((ext_vector_type(8)));
typedef short short4v __attribute__((ext_vector_type(4)));

DEV unsigned short f2bf(float f) {
    union { float f; unsigned u; } c; c.f = f;
    unsigned u = c.u;
    u += 0x7fffu + ((u >> 16) & 1u);   // round-to-nearest-even
    return (unsigned short)(u >> 16);
}

DEV void async_ld16(const void* g, void* l) {
    __builtin_amdgcn_global_load_lds(
        (const __attribute__((address_space(1))) unsigned int*)g,
        (__attribute__((address_space(3))) unsigned int*)l, 16, 0, 0);
}

DEV f32x4 mfma16(bf16x8 a, bf16x8 b, f32x4 c) {
    return __builtin_amdgcn_mfma_f32_16x16x32_bf16(a, b, c, 0, 0, 0);
}

// ---------------- k_prep: fused x->bf16 cvt + W transpose -------------------
// blocks [0,4096): cvt; [4096,4864): trw
__global__ __launch_bounds__(256) void k_prep(const float* __restrict__ x,
                                              const float* __restrict__ W,
                                              unsigned short* __restrict__ xb,
                                              unsigned short* __restrict__ Wt) {
    __shared__ float T[64][65];
    int blk = blockIdx.x;
    if (blk < 4096) {
        int t = blk * 256 + threadIdx.x;
        const float4* xp = (const float4*)x;
        float4 a = xp[t * 2], b = xp[t * 2 + 1];
        short8 o;
        o[0] = (short)f2bf(a.x); o[1] = (short)f2bf(a.y);
        o[2] = (short)f2bf(a.z); o[3] = (short)f2bf(a.w);
        o[4] = (short)f2bf(b.x); o[5] = (short)f2bf(b.y);
        o[6] = (short)f2bf(b.z); o[7] = (short)f2bf(b.w);
        *(short8*)(xb + t * 8) = o;
    } else {
        int bx = blk - 4096;
        int n0 = (bx % 48) * 64, k0 = (bx / 48) * 64;
        int t = threadIdx.x;
        int r = t >> 4, c4 = (t & 15) * 4;
        for (int i = 0; i < 4; i++) {
            int row = r + i * 16;
            float4 v = *(const float4*)(W + (k0 + row) * 3072 + n0 + c4);
            T[row][c4] = v.x; T[row][c4 + 1] = v.y; T[row][c4 + 2] = v.z; T[row][c4 + 3] = v.w;
        }
        __syncthreads();
        for (int i = 0; i < 4; i++) {
            int nrow = r + i * 16;
            short4v o;
            o[0] = (short)f2bf(T[c4 + 0][nrow]);
            o[1] = (short)f2bf(T[c4 + 1][nrow]);
            o[2] = (short)f2bf(T[c4 + 2][nrow]);
            o[3] = (short)f2bf(T[c4 + 3][nrow]);
            *(short4v*)(Wt + (n0 + nrow) * 1024 + k0 + c4) = o;
        }
    }
}

// ---------------- QKV GEMM: [8192x1024]x[1024x3072] + bias, scatter --------
// Q stored [bh][n][d] scaled x32; K,V stored transposed [bh][d][n]
__global__ __launch_bounds__(256, 2) void k_qkv(const unsigned short* __restrict__ xb,
                                                const unsigned short* __restrict__ Wt,
                                                const float* __restrict__ bias,
                                                unsigned short* __restrict__ Q,
                                                unsigned short* __restrict__ K,
                                                unsigned short* __restrict__ V) {
    __shared__ __align__(16) unsigned short As[128 * 64];  // XOR-swizzled chunks (mask 7)
    __shared__ __align__(16) unsigned short Bs[128 * 64];
    const int m0 = blockIdx.y * 128, n0 = blockIdx.x * 128;
    const int wave = threadIdx.x >> 6, lane = threadIdx.x & 63;
    const int wm = (wave & 1) * 64, wn = (wave >> 1) * 64;
    f32x4 acc[4][4] = {};
    const int slr = wave * 32 + (lane >> 3);  // staging local row (+ i*8)
    const int scs = lane & 7;                 // staging chunk slot

    for (int kt = 0; kt < 16; kt++) {
        __syncthreads();
        for (int i = 0; i < 4; i++) {
            int lr = slr + i * 8;
            int c = scs ^ (lr & 7);
            async_ld16(xb + (m0 + lr) * 1024 + kt * 64 + c * 8,
                       (void*)(As + (wave * 32 + i * 8) * 64));
            async_ld16(Wt + (n0 + lr) * 1024 + kt * 64 + c * 8,
                       (void*)(Bs + (wave * 32 + i * 8) * 64));
        }
        __syncthreads();
        for (int ks = 0; ks < 2; ks++) {
            bf16x8 af[4], bfr[4];
            int c0 = ks * 4 + (lane >> 4);
            for (int tm = 0; tm < 4; tm++) {
                int row = wm + tm * 16 + (lane & 15);
                af[tm] = *(const bf16x8*)(As + row * 64 + (c0 ^ (row & 7)) * 8);
            }
            for (int tn = 0; tn < 4; tn++) {
                int row = wn + tn * 16 + (lane & 15);
                bfr[tn] = *(const bf16x8*)(Bs + row * 64 + (c0 ^ (row & 7)) * 8);
            }
            for (int tm = 0; tm < 4; tm++)
                for (int tn = 0; tn < 4; tn++)
                    acc[tm][tn] = mfma16(af[tm], bfr[tn], acc[tm][tn]);
        }
    }

    // epilogue: bias + scatter. col -> (h = c/192, d = (c%192)/3, which = c%3)
    // K/V: 4 consecutive tokens per lane -> packed 8B store.
    const int batch = m0 >> 11;
    for (int tn = 0; tn < 4; tn++) {
        int col = n0 + wn + tn * 16 + (lane & 15);
        int h = col / 192;
        int rem = col - h * 192;
        int d = rem / 3;
        int which = rem - d * 3;
        float bv = bias[col];
        int bh = batch * 16 + h;
        unsigned q_base = (unsigned)bh * 131072u + (unsigned)d;          // [bh][n][d]
        unsigned kv_base = ((unsigned)bh * 64u + (unsigned)d) * 2048u;   // [bh][d][n]
        unsigned short* dst = which == 0 ? Q : (which == 1 ? K : V);
        for (int tm = 0; tm < 4; tm++) {
            int rbase = m0 + wm + tm * 16 + ((lane >> 4) * 4);
            unsigned token0 = (unsigned)(rbase & 2047);
            float v0 = acc[tm][tn][0] + bv;
            float v1 = acc[tm][tn][1] + bv;
            float v2 = acc[tm][tn][2] + bv;
            float v3 = acc[tm][tn][3] + bv;
            if (which == 0) {
                unsigned idx = q_base + token0 * 64u;   // fold scale 32 into Q
                dst[idx]        = f2bf(v0 * 32.0f);
                dst[idx + 64u]  = f2bf(v1 * 32.0f);
                dst[idx + 128u] = f2bf(v2 * 32.0f);
                dst[idx + 192u] = f2bf(v3 * 32.0f);
            } else {
                uint2 p;
                p.x = (unsigned)f2bf(v0) | ((unsigned)f2bf(v1) << 16);
                p.y = (unsigned)f2bf(v2) | ((unsigned)f2bf(v3) << 16);
                *(uint2*)(dst + kv_base + token0) = p;
            }
        }
    }
}

// ---------------- k_attn3: per-head redundant M = K^T V, then out = Q.M ----
// grid 512: bh = blockIdx & 63 (all 8 sub-blocks of a head land on one XCD:
// blockIdx % 8 == bh % 8), sub = blockIdx >> 6. No cross-block deps, no
// atomics: each block computes its head's full 64x64 M (4 waves x 512 tokens),
// reduces via LDS, then computes out rows [sub*256, +256).
__global__ __launch_bounds__(256) void k_attn3(const unsigned short* __restrict__ Kt,
                                               const unsigned short* __restrict__ Vt,
                                               const unsigned short* __restrict__ Q,
                                               float* __restrict__ out) {
    __shared__ __align__(16) float Ps[4][4096];          // 64KB wave partials
    __shared__ __align__(16) unsigned short Msb[4096];   // 8KB bf16 M, swizzled
    const int bh = blockIdx.x & 63, sub = blockIdx.x >> 6;
    const int wave = threadIdx.x >> 6, lane = threadIdx.x & 63;
    const int lan15 = lane & 15, quad = lane >> 4;
    const unsigned base = (unsigned)bh * 131072u;

    // ---- phase A: acc[d1-tile][d2-tile] += K^T V over this wave's 512 tokens
    f32x4 acc[4][4] = {};
    for (int it = 0; it < 16; it++) {
        int no = wave * 512 + it * 32 + quad * 8;
        bf16x8 af[4], bfr[4];
        for (int mt = 0; mt < 4; mt++)
            af[mt] = *(const bf16x8*)(Kt + base + (unsigned)(mt * 16 + lan15) * 2048u + no);
        for (int nt = 0; nt < 4; nt++)
            bfr[nt] = *(const bf16x8*)(Vt + base + (unsigned)(nt * 16 + lan15) * 2048u + no);
        for (int mt = 0; mt < 4; mt++)
            for (int nt = 0; nt < 4; nt++)
                acc[mt][nt] = mfma16(af[mt], bfr[nt], acc[mt][nt]);
    }
    for (int mt = 0; mt < 4; mt++)
        for (int nt = 0; nt < 4; nt++)
            *(f32x4*)(&Ps[wave][((mt * 4 + nt) * 64 + lane) * 4]) = acc[mt][nt];
    __syncthreads();

    // ---- reduce 4 wave-partials, decode C-layout -> (d1,d2), bf16 to Msb ----
    {
        int e0 = threadIdx.x * 16;
        for (int j = 0; j < 4; j++) {
            f32x4 m = *(const f32x4*)(&Ps[0][e0 + j * 4]);
            for (int s = 1; s < 4; s++) {
                f32x4 p = *(const f32x4*)(&Ps[s][e0 + j * 4]);
                m.x += p.x; m.y += p.y; m.z += p.z; m.w += p.w;
            }
            for (int r = 0; r < 4; r++) {
                int e = e0 + j * 4 + r;
                int tile = e >> 8, le = (e >> 2) & 63;
                int d1 = (tile >> 2) * 16 + ((le >> 4) << 2) + r;
                int d2 = (tile & 3) * 16 + (le & 15);
                Msb[d2 * 64 + (((d1 >> 3) ^ (d2 & 7)) << 3) + (d1 & 7)] = f2bf(m[r]);
            }
        }
    }
    __syncthreads();

    // ---- phase B: out tile = Q(x32)[sub*256 + wave*64 ..] . M ----
    {
        const int q0w = sub * 256 + wave * 64;
        f32x4 oacc[4][4] = {};
#pragma unroll
        for (int ks = 0; ks < 2; ks++) {
            bf16x8 af[4], bfr[4];
            for (int mt = 0; mt < 4; mt++)
                af[mt] = *(const bf16x8*)(Q + base + (unsigned)(q0w + mt * 16 + lan15) * 64u +
                                          ks * 32 + quad * 8);
            for (int nt = 0; nt < 4; nt++) {
                int d2 = nt * 16 + lan15;
                bfr[nt] = *(const bf16x8*)(Msb + d2 * 64 + (((ks * 4 + quad) ^ (d2 & 7)) << 3));
            }
            for (int mt = 0; mt < 4; mt++)
                for (int nt = 0; nt < 4; nt++)
                    oacc[mt][nt] = mfma16(af[mt], bfr[nt], oacc[mt][nt]);
        }
        for (int mt = 0; mt < 4; mt++)
            for (int nt = 0; nt < 4; nt++)
                for (int r = 0; r < 4; r++)
                    out[base + (unsigned)(q0w + mt * 16 + quad * 4 + r) * 64u + nt * 16 + lan15] =
                        oacc[mt][nt][r];
    }
}

extern "C" void kernel_launch(void* const* d_in, const int* in_sizes, int n_in,
                              void* d_out, int out_size, void* d_ws, size_t ws_size,
                              hipStream_t stream) {
    const float* x = (const float*)d_in[0];
    const float* W = (const float*)d_in[1];
    const float* b = (const float*)d_in[2];
    float* out = (float*)d_out;

    unsigned short* xb = (unsigned short*)d_ws;   // 8,388,608 bf16 (16 MB)
    unsigned short* Wt = xb + 8388608;            // 3,145,728 bf16 (6 MB)
    unsigned short* Qb = Wt + 3145728;            // 8,388,608 bf16 (scaled by 32)
    unsigned short* Kt = Qb + 8388608;            // 8,388,608 bf16, [bh][d][n]
    unsigned short* Vt = Kt + 8388608;            // 8,388,608 bf16, [bh][d][n]
    // total workspace: ~70 MB

    k_prep<<<4864, 256, 0, stream>>>(x, W, xb, Wt);
    k_qkv<<<dim3(24, 64), 256, 0, stream>>>(xb, Wt, b, Qb, Kt, Vt);
    k_attn3<<<512, 256, 0, stream>>>(Kt, Vt, Qb, out);
}